// Round 5
// baseline (321.357 us; speedup 1.0000x reference)
//
#include <hip/hip_runtime.h>
#include <cstdint>
#include <cstddef>

// Problem shape (fixed by the reference setup_inputs)
#define MDIM 8192
#define KDIM 2048
#define NDIM 2048
#define QBLK 128
#define KB   (KDIM / QBLK)   // 16
#define NB   (NDIM / QBLK)   // 16

typedef float floatx4 __attribute__((ext_vector_type(4)));
typedef int   int4v   __attribute__((ext_vector_type(4)));
typedef int   int8v   __attribute__((ext_vector_type(8)));

#define AS1 __attribute__((address_space(1)))
#define AS3 __attribute__((address_space(3)))

// ---------------------------------------------------------------------------
// fp8 e4m3fn helpers (software, bit-exact)
// ---------------------------------------------------------------------------
__device__ inline float e4m3_rne(float q) {     // RNE to fp8 grid, |q| <= 448
    float aq = fabsf(q);
    float r;
    if (aq < 0.015625f) {                        // subnormal: grid 2^-9
        r = rintf(aq * 512.0f) * 0.001953125f;
    } else {
        unsigned u = __float_as_uint(aq);
        unsigned rem = u & 0xFFFFFu;
        unsigned base = u & ~0xFFFFFu;
        unsigned inc = (rem > 0x80000u || (rem == 0x80000u && (u & 0x100000u))) ? 0x100000u : 0u;
        r = __uint_as_float(base + inc);
    }
    return q < 0.0f ? -r : r;
}

__device__ inline unsigned e4m3_encode(float r) {  // r exactly on fp8 grid
    unsigned u = __float_as_uint(r);
    unsigned s = (u >> 24) & 0x80u;
    float a = fabsf(r);
    if (a < 0.015625f) return s | (unsigned)(a * 512.0f + 0.25f);
    unsigned e = ((u >> 23) & 0xFFu) - 120u;       // 1..15
    unsigned m = (u >> 20) & 7u;
    return s | (e << 3) | m;
}

__device__ inline int is_expbyte(unsigned b) {   // plausible f32/bf16 hi byte for fp8-exact value
    unsigned e = b & 0x7Fu;
    return (e >= 0x3Bu && e <= 0x43u) || e == 0x00u;
}

// ---------------------------------------------------------------------------
// Workspace layout
//   xq  [M][K]  fp8 bytes            @ 0        (16 MB)
//   wq8 [N][K]  fp8 bytes            @ 16 MB    (4 MB)
//   xs  [M][KB] f32 act scales       @ 20 MB    (512 KB)
// ---------------------------------------------------------------------------
#define XQ_OFF  0
#define WQ_OFF  ((size_t)MDIM * KDIM)
#define XS_OFF  (WQ_OFF + (size_t)NDIM * KDIM)

#define QXB ((MDIM * KB) / 8)          // 16384 act-quant blocks
#define DWB ((NDIM * KDIM / 8) / 256)  // 2048 weight blocks

// ---------------------------------------------------------------------------
// Prep: act quant -> fp8 bytes + scales; weight -> fp8 bytes (delivery-format
// classified inline per wave via ballot over the first 256 bytes).
// ---------------------------------------------------------------------------
__global__ __launch_bounds__(256) void prep_kernel(const float* __restrict__ x,
                                                   const void* __restrict__ wq,
                                                   unsigned char* __restrict__ xq,
                                                   unsigned char* __restrict__ wq8,
                                                   float* __restrict__ xs) {
    const int tid = threadIdx.x;
    if (blockIdx.x < QXB) {
        // ---- activation quant: one 32-lane group per (1,128) block ----
        const int g = tid >> 5;
        const int l = tid & 31;
        const size_t bi = (size_t)blockIdx.x * 8 + g;    // = m*KB + kb
        const size_t base = bi << 7;

        const float4 v = *(const float4*)(x + base + (size_t)l * 4);
        float a = fmaxf(fmaxf(fabsf(v.x), fabsf(v.y)), fmaxf(fabsf(v.z), fabsf(v.w)));
        a = fmaxf(a, __shfl_xor(a, 1));
        a = fmaxf(a, __shfl_xor(a, 2));
        a = fmaxf(a, __shfl_xor(a, 4));
        a = fmaxf(a, __shfl_xor(a, 8));
        a = fmaxf(a, __shfl_xor(a, 16));

        const float scale = fmaxf(a, 1e-12f) / 448.0f;
        if (l == 0) xs[bi] = scale;

        unsigned b0 = e4m3_encode(e4m3_rne(v.x / scale));
        unsigned b1 = e4m3_encode(e4m3_rne(v.y / scale));
        unsigned b2 = e4m3_encode(e4m3_rne(v.z / scale));
        unsigned b3 = e4m3_encode(e4m3_rne(v.w / scale));
        *(unsigned*)(xq + base + (size_t)l * 4) = b0 | (b1 << 8) | (b2 << 16) | (b3 << 24);
    } else {
        // ---- weight repack to fp8 bytes ----
        const int lane = tid & 63;
        const unsigned pw = ((const unsigned*)wq)[lane];
        const unsigned long long m3 = __ballot(is_expbyte((pw >> 24) & 0xFFu));
        const unsigned long long m1 = __ballot(((pw >> 8) & 0xFFu) == 0u);
        const int f = (__popcll(m3) >= 56) ? ((__popcll(m1) >= 56) ? 2 : 1) : 0;

        const size_t idx = (size_t)(blockIdx.x - QXB) * 256 + tid;
        const size_t off = idx * 8;

        unsigned lo, hi;
        if (f == 2) {              // float32 upcast delivery
            const float4* p = (const float4*)((const float*)wq + off);
            const float4 a = p[0], b = p[1];
            lo = e4m3_encode(a.x) | (e4m3_encode(a.y) << 8) | (e4m3_encode(a.z) << 16) | (e4m3_encode(a.w) << 24);
            hi = e4m3_encode(b.x) | (e4m3_encode(b.y) << 8) | (e4m3_encode(b.z) << 16) | (e4m3_encode(b.w) << 24);
        } else if (f == 1) {       // bf16 upcast delivery
            const ushort4 h0 = *(const ushort4*)((const unsigned short*)wq + off);
            const ushort4 h1 = *(((const ushort4*)((const unsigned short*)wq + off)) + 1);
            lo = e4m3_encode(__uint_as_float((unsigned)h0.x << 16))
               | (e4m3_encode(__uint_as_float((unsigned)h0.y << 16)) << 8)
               | (e4m3_encode(__uint_as_float((unsigned)h0.z << 16)) << 16)
               | (e4m3_encode(__uint_as_float((unsigned)h0.w << 16)) << 24);
            hi = e4m3_encode(__uint_as_float((unsigned)h1.x << 16))
               | (e4m3_encode(__uint_as_float((unsigned)h1.y << 16)) << 8)
               | (e4m3_encode(__uint_as_float((unsigned)h1.z << 16)) << 16)
               | (e4m3_encode(__uint_as_float((unsigned)h1.w << 16)) << 24);
        } else {                   // already raw fp8 bytes
            const uint2 d = *(const uint2*)((const unsigned char*)wq + off);
            lo = d.x; hi = d.y;
        }
        *(uint2*)(wq8 + off) = make_uint2(lo, hi);
    }
}

// ---------------------------------------------------------------------------
// GEMM: MX fp8, K=128 per MFMA (= one quant block), HW scales = 1.0, per-block
// fp32 scale applied as VALU fixup (layout HW-validated in R4 via on-device
// check kernel + absmax at comparison noise floor).
// 128x128 tile, 4 waves (2x2 of 64x64), global_load_lds width-16 staging,
// XOR-swizzled 16B chunks. R5: xs scale tile preloaded to LDS (kills per-iter
// scattered global loads); LDS 40 KB + VGPR<=128 -> 4 blocks/CU for
// inter-block stage/compute overlap (the m114 mechanism).
// A/B fragment layout (HW-validated R4): row = lane&15, k = (lane>>4)*32 + byte.
// ---------------------------------------------------------------------------
__global__ __launch_bounds__(256, 4) void gemm_mx_kernel(const unsigned char* __restrict__ Aq,
                                                         const unsigned char* __restrict__ Bq,
                                                         const float* __restrict__ xs,
                                                         const float* __restrict__ wsc,
                                                         float* __restrict__ C) {
    __shared__ unsigned char sA[128 * 128];   // 16 KB
    __shared__ unsigned char sB[128 * 128];   // 16 KB
    __shared__ float sXS[128 * KB];           // 8 KB: per-row, per-kb act scales

    const int tid  = threadIdx.x;
    const int wave = tid >> 6;
    const int lane = tid & 63;
    const int lrow = lane & 15;
    const int lk   = lane >> 4;          // k-group (32 bytes each)
    const int wm   = (wave & 1) * 64;
    const int wn   = (wave >> 1) * 64;
    const int m0   = blockIdx.y * 128;
    const int n0   = blockIdx.x * 128;
    const int nb   = n0 >> 7;

    // xs tile preload: 128 rows x 16 kb = 2048 floats; 8 per thread.
    {
        const float4* src = (const float4*)(xs + (size_t)m0 * KB) + tid * 2;
        float4* dst = (float4*)sXS + tid * 2;
        dst[0] = src[0];
        dst[1] = src[1];
    }

    // staging: thread t -> LDS bytes [t*16 + it*4096): row = t/8 + it*32,
    // physical chunk = t&7 holding logical chunk (t&7)^(row&7).
    const int srow = tid >> 3;
    const int gck  = (tid & 7) ^ (srow & 7);
    const unsigned char* agp = Aq + (size_t)(m0 + srow) * KDIM + gck * 16;
    const unsigned char* bgp = Bq + (size_t)(n0 + srow) * KDIM + gck * 16;

    floatx4 acc[4][4] = {};
    const floatx4 zero = {0.f, 0.f, 0.f, 0.f};

    for (int kb = 0; kb < KB; ++kb) {            // 16 iterations, 128 K each
        const size_t koff = (size_t)kb * QBLK;   // byte offset in a row
        __syncthreads();                         // LDS reuse guard (covers sXS at kb=0)
#pragma unroll
        for (int it = 0; it < 4; ++it)
            __builtin_amdgcn_global_load_lds(
                (const AS1 void*)(agp + (size_t)(it * 32) * KDIM + koff),
                (AS3 void*)(sA + tid * 16 + it * 4096), 16, 0, 0);
#pragma unroll
        for (int it = 0; it < 4; ++it)
            __builtin_amdgcn_global_load_lds(
                (const AS1 void*)(bgp + (size_t)(it * 32) * KDIM + koff),
                (AS3 void*)(sB + tid * 16 + it * 4096), 16, 0, 0);
        __syncthreads();

        // fragments: logical bytes [lk*32, lk*32+32) of each row
        int8v af[4], bf[4];
#pragma unroll
        for (int i = 0; i < 4; ++i) {
            const int Ra = wm + i * 16 + lrow;
            const int c0 = (lk * 2) ^ (Ra & 7);
            const int c1 = (lk * 2 + 1) ^ (Ra & 7);
            int4v alo = *(const int4v*)(sA + Ra * 128 + c0 * 16);
            int4v ahi = *(const int4v*)(sA + Ra * 128 + c1 * 16);
            af[i] = __builtin_shufflevector(alo, ahi, 0, 1, 2, 3, 4, 5, 6, 7);
            const int Rb = wn + i * 16 + lrow;
            const int d0 = (lk * 2) ^ (Rb & 7);
            const int d1 = (lk * 2 + 1) ^ (Rb & 7);
            int4v blo = *(const int4v*)(sB + Rb * 128 + d0 * 16);
            int4v bhi = *(const int4v*)(sB + Rb * 128 + d1 * 16);
            bf[i] = __builtin_shufflevector(blo, bhi, 0, 1, 2, 3, 4, 5, 6, 7);
        }

        // combined per-row scales for this k-block (C/D row = lk*4 + r),
        // act scales from LDS (broadcast reads), weight scale wave-uniform.
        const float wsk = wsc[nb * KB + kb];
        float cs[4][4];
#pragma unroll
        for (int i = 0; i < 4; ++i)
#pragma unroll
            for (int r = 0; r < 4; ++r)
                cs[i][r] = sXS[(wm + i * 16 + lk * 4 + r) * KB + kb] * wsk;

#pragma unroll
        for (int i = 0; i < 4; ++i)
#pragma unroll
            for (int j = 0; j < 4; ++j) {
                floatx4 blk = __builtin_amdgcn_mfma_scale_f32_16x16x128_f8f6f4(
                    af[i], bf[j], zero, 0, 0, 0, 0x7F7F7F7F, 0, 0x7F7F7F7F);
#pragma unroll
                for (int r = 0; r < 4; ++r)
                    acc[i][j][r] += cs[i][r] * blk[r];
            }
    }

    // Epilogue: col = lane&15, row = lk*4 + r.
#pragma unroll
    for (int i = 0; i < 4; ++i) {
        const int row0 = m0 + wm + i * 16 + lk * 4;
#pragma unroll
        for (int r = 0; r < 4; ++r) {
            float* cp = C + (size_t)(row0 + r) * NDIM + n0 + wn + lrow;
#pragma unroll
            for (int j = 0; j < 4; ++j)
                cp[j * 16] = acc[i][j][r];
        }
    }
}

// ---------------------------------------------------------------------------
extern "C" void kernel_launch(void* const* d_in, const int* in_sizes, int n_in,
                              void* d_out, int out_size, void* d_ws, size_t ws_size,
                              hipStream_t stream) {
    const float* x      = (const float*)d_in[0];
    const void* wq      = d_in[1];
    const float* wscale = (const float*)d_in[2];
    float* y            = (float*)d_out;

    unsigned char* xq  = (unsigned char*)d_ws + XQ_OFF;
    unsigned char* wq8 = (unsigned char*)d_ws + WQ_OFF;
    float* xs          = (float*)((unsigned char*)d_ws + XS_OFF);

    prep_kernel<<<QXB + DWB, 256, 0, stream>>>(x, wq, xq, wq8, xs);
    gemm_mx_kernel<<<dim3(NDIM / 128, MDIM / 128), 256, 0, stream>>>(xq, wq8, xs, wscale, y);
}